// Round 19
// baseline (754.690 us; speedup 1.0000x reference)
//
#include <hip/hip_runtime.h>
#include <hip/hip_bf16.h>

// ---------------------------------------------------------------------------
// FEDformer forward. bf16 MFMA everywhere, fp32 residual stream + bf16 shadow.
// DFT-first spectral path. mgemm: 2-buffer 2-barrier counted-vmcnt pipeline
// + chunk-XOR LDS swizzle + bijective XCD block swizzle + s_setprio around
// the MFMA cluster (T5; waves sit at different K-steps at 2 blocks/CU, so
// priority arbitration has role-diversity to exploit). BK=64 where
// grid-limited (FFN2, DFT, spectral); FFN1 BK=32 (LDS-capped occupancy).
// modemix reads PACKED bf16-pair weights (4MB/h = one XCD L2 slice).
// B=32, N_NODES=200, T=512, D=512, H=8, HD=64, MODES=64, L=4, D_CONV=2048.
// ---------------------------------------------------------------------------

typedef short s16x8 __attribute__((ext_vector_type(8)));
typedef float f32x4 __attribute__((ext_vector_type(4)));
typedef unsigned short us;

#define GLOAD16(gp, lp)                                                        \
    __builtin_amdgcn_global_load_lds(                                          \
        (const __attribute__((address_space(1))) void*)(gp),                   \
        (__attribute__((address_space(3))) void*)(lp), 16, 0, 0)

__device__ __forceinline__ us f2b(float v) {
    __hip_bfloat16 h = __float2bfloat16(v);
    return *(us*)&h;
}
__device__ __forceinline__ float b2f(us u) {
    __hip_bfloat16_raw r; r.x = u;
    return __bfloat162float(__hip_bfloat16(r));
}

template <int N> __device__ __forceinline__ void vmwait() {
    if constexpr (N == 0)      asm volatile("s_waitcnt vmcnt(0)" ::: "memory");
    else if constexpr (N == 2) asm volatile("s_waitcnt vmcnt(2)" ::: "memory");
    else if constexpr (N == 3) asm volatile("s_waitcnt vmcnt(3)" ::: "memory");
    else if constexpr (N == 4) asm volatile("s_waitcnt vmcnt(4)" ::: "memory");
    else if constexpr (N == 6) asm volatile("s_waitcnt vmcnt(6)" ::: "memory");
    else if constexpr (N == 8) asm volatile("s_waitcnt vmcnt(8)" ::: "memory");
    else                       asm volatile("s_waitcnt vmcnt(0)" ::: "memory");
}

// EPI: 0 = bf16 store, 2 = relu bf16 store,
//      3 = fp32 C += acc + plain bf16 shadow (iDFT),
//      4 = fp32 store (acc + peb) + TRANSPOSED shadow (embed),
//      5 = fp32 C += acc (no shadow, last FFN2),
//      6 = bf16 store + DC-row bias (spectral), 7 = fp32 C += acc +
//      TRANSPOSED shadow (FFN2 l<3).
// Tile: BM x BN x BK, 4 waves 2x2; NT GEMM C[m][n] = sum_k A[m][k]*B[n][k].
// Logical grid: n fastest, then m, then batch — decoded from an XCD-swizzled
// flat id so logically-adjacent (A-sharing) blocks land on the same XCD.
template <int EPI, int BM, int BN, int BK = 32>
__global__ __launch_bounds__(256) void mgemm_k(
    const us* __restrict__ Ap, const us* __restrict__ Bp,
    void* __restrict__ Cp, us* __restrict__ Sp, int M, int N, int K,
    long long a_batch, long long b_batch, long long c_batch,
    const float* __restrict__ bias, long long srow)
{
    constexpr int WM = BM / 2;
    constexpr int WN = BN / 2;
    constexpr int MI = WM / 16;
    constexpr int NJ = WN / 16;
    constexpr int KS = BK / 32;               // k-slices per K-step (1 or 2)
    constexpr int LA = BM * BK / 512;         // A global_load_lds per stage
    constexpr int LB = BN * BK / 512;
    constexpr int LT = LA + LB;               // divisible by 4
    constexpr int LPW = LT / 4;               // loads per wave per stage
    constexpr int HALF = (BM + BN) * BK;      // us per staging buffer
    constexpr int EBS = BN + 2;               // epilogue LDS row stride (f32)
    constexpr int SG = 2 * HALF * 2;
    constexpr int SE = 32 * EBS * 4;
    constexpr int SMEM = SG > SE ? SG : SE;
    __shared__ __align__(16) char smem[SMEM];
    float* eb = (float*)smem;

    // ---- bijective XCD swizzle: physical p -> logical fid ----
    const int gx = gridDim.x, gy = gridDim.y;
    const int tot = gx * gy * gridDim.z;
    int p = (blockIdx.z * gy + blockIdx.y) * gx + blockIdx.x;
    int fid = ((tot & 7) == 0) ? ((p & 7) * (tot >> 3) + (p >> 3)) : p;
    const int bn = fid % gx;
    const int t2 = fid / gx;
    const int bm = t2 % gy;
    const int bz = t2 / gy;

    const us* A = Ap + (long long)bz * a_batch + (long long)bm * BM * K;
    const us* B = Bp + (long long)bz * b_batch + (long long)bn * BN * K;
    const int tid  = threadIdx.x;
    const int wave = tid >> 6, lane = tid & 63;
    const int wr = wave >> 1, wc = wave & 1;

    f32x4 acc[MI][NJ] = {};

    const int frow = lane & 15;

    // staging/read addressing (linear LDS dest, XOR-swizzled global source):
    // BK=32: rows of 64B, 4 chunks of 16B; swizzle s(r) = (r>>1)&3.
    // BK=64: rows of 128B, 8 chunks of 16B; swizzle s(r) = r&7.
    const int r32  = lane >> 2;
    const int kb32 = ((lane & 3) ^ ((lane >> 3) & 3)) * 8;
    const int fko32 = ((lane >> 4) ^ ((frow >> 1) & 3)) * 8;
    const int r64  = lane >> 3;
    const int kb64 = ((lane & 7) ^ (lane >> 3)) * 8;

    auto stage = [&](int k0, int bsel) {
        const us* Ag = A + k0;
        const us* Bg = B + k0;
        us* Ad = (us*)smem + bsel * HALF;
        us* Bd = Ad + BM * BK;
        #pragma unroll
        for (int ii = 0; ii < LPW; ++ii) {
            const int i = ii * 4 + wave;
            if constexpr (BK == 32) {
                if (i < LA)
                    GLOAD16(Ag + (long long)(i * 16 + r32) * K + kb32,
                            Ad + i * 512);
                else
                    GLOAD16(Bg + (long long)((i - LA) * 16 + r32) * K + kb32,
                            Bd + (i - LA) * 512);
            } else {
                if (i < LA)
                    GLOAD16(Ag + (long long)(i * 8 + r64) * K + kb64,
                            Ad + i * 512);
                else
                    GLOAD16(Bg + (long long)((i - LA) * 8 + r64) * K + kb64,
                            Bd + (i - LA) * 512);
            }
        }
    };

    const int NK = K / BK;
    stage(0, 0);
    int cur = 0;
    for (int k = 0; k < NK; ++k) {
        if (k + 1 < NK) {
            stage((k + 1) * BK, cur ^ 1);  // loads span the whole iteration
            vmwait<LPW>();                 // only buf-cur loads (oldest) done
        } else {
            vmwait<0>();
        }
        __builtin_amdgcn_s_barrier();      // buf cur fully staged (all waves)

        const us* Ab = (const us*)smem + cur * HALF;
        const us* Bb = Ab + BM * BK;
        s16x8 af[MI][KS], bfr[NJ][KS];
        if constexpr (BK == 32) {
            #pragma unroll
            for (int i = 0; i < MI; ++i)
                af[i][0] = *(const s16x8*)
                    &Ab[(wr * WM + i * 16 + frow) * 32 + fko32];
            #pragma unroll
            for (int j = 0; j < NJ; ++j)
                bfr[j][0] = *(const s16x8*)
                    &Bb[(wc * WN + j * 16 + frow) * 32 + fko32];
        } else {
            #pragma unroll
            for (int ks = 0; ks < KS; ++ks) {
                const int off = (((ks * 4 + (lane >> 4)) ^ (frow & 7))) * 8;
                #pragma unroll
                for (int i = 0; i < MI; ++i)
                    af[i][ks] = *(const s16x8*)
                        &Ab[(wr * WM + i * 16 + frow) * 64 + off];
                #pragma unroll
                for (int j = 0; j < NJ; ++j)
                    bfr[j][ks] = *(const s16x8*)
                        &Bb[(wc * WN + j * 16 + frow) * 64 + off];
            }
        }
        __builtin_amdgcn_s_setprio(1);     // T5: favor MFMA-entering waves
        #pragma unroll
        for (int i = 0; i < MI; ++i)
            #pragma unroll
            for (int j = 0; j < NJ; ++j)
                #pragma unroll
                for (int ks = 0; ks < KS; ++ks)
                    acc[i][j] = __builtin_amdgcn_mfma_f32_16x16x32_bf16(
                        af[i][ks], bfr[j][ks], acc[i][j], 0, 0, 0);
        __builtin_amdgcn_s_setprio(0);

        __builtin_amdgcn_s_barrier();      // all reads of cur done (no drain)
        cur ^= 1;
    }

    // ---- coalesced epilogue: BM/32 passes of 32 rows through LDS ----
    const long long Coff = (long long)bz * c_batch;
    const int row_blk = bm * BM;
    const int col_blk = bn * BN;
    constexpr int RPI = 256 / BN;
    #pragma unroll
    for (int pp = 0; pp < BM / 32; ++pp) {
        __syncthreads();
        #pragma unroll
        for (int rb2 = 0; rb2 < 2; ++rb2) {
            const int rb = pp * 2 + rb2;
            if (wr == rb / MI) {
                const int io = rb % MI;
                #pragma unroll
                for (int j = 0; j < NJ; ++j) {
                    #pragma unroll
                    for (int rr = 0; rr < 4; ++rr) {
                        const int lrow = rb2 * 16 + (lane >> 4) * 4 + rr;
                        const int lcol = wc * WN + j * 16 + (lane & 15);
                        eb[lrow * EBS + lcol] = acc[io][j][rr];
                    }
                }
            }
        }
        __syncthreads();
        #pragma unroll
        for (int it = 0; it < 32 / RPI; ++it) {
            const int lrow = it * RPI + tid / BN;
            const int row  = row_blk + pp * 32 + lrow;
            const int col  = col_blk + (tid % BN);
            float v = eb[lrow * EBS + (tid % BN)];
            const long long cidx = Coff + (long long)row * N + col;
            if (EPI == 0) {
                ((us*)Cp)[cidx] = f2b(v);
            } else if (EPI == 2) {
                ((us*)Cp)[cidx] = f2b(fmaxf(v, 0.f));
            } else if (EPI == 3) {
                float nv = ((float*)Cp)[cidx] + v;
                ((float*)Cp)[cidx] = nv;
                Sp[cidx] = f2b(nv);
            } else if (EPI == 4) {
                float nv = v + bias[(long long)row * 512 + col];
                ((float*)Cp)[cidx] = nv;
                eb[lrow * EBS + (tid % BN)] = nv;    // for transposed pass
            } else if (EPI == 5) {
                ((float*)Cp)[cidx] += v;
            } else if (EPI == 6) {
                if (row == 0) v += 512.f * bias[col];
                ((us*)Cp)[cidx] = f2b(v);
            } else {  // EPI == 7
                float nv = ((float*)Cp)[cidx] + v;
                ((float*)Cp)[cidx] = nv;
                eb[lrow * EBS + (tid % BN)] = nv;    // for transposed pass
            }
        }
        if constexpr (EPI == 4 || EPI == 7) {
            // transposed shadow: Sp[b][d][t], 32 t x BN d tile
            __syncthreads();
            constexpr int TPC = 256 / BN;          // threads per column
            constexpr int RPT = 32 / TPC;          // rows per thread
            const int dl = tid / TPC;              // 0..BN-1
            const int th = (tid % TPC) * RPT;      // starting row
            const long long R = (long long)bz * M + srow
                              + row_blk + pp * 32; // global row (b*512+t)
            const int bb = (int)(R >> 9);
            const int tb = (int)(R & 511);
            us* tp = Sp + (long long)bb * 262144
                        + (long long)(col_blk + dl) * 512 + tb + th;
            #pragma unroll
            for (int v8 = 0; v8 < RPT / 8; ++v8) {
                s16x8 vv;
                #pragma unroll
                for (int i = 0; i < 8; ++i)
                    vv[i] = (short)f2b(eb[(th + v8 * 8 + i) * EBS + dl]);
                *(s16x8*)(tp + v8 * 8) = vv;
            }
        }
    }
}

// Build bf16 DFT tables. FT: [128][512] (mm,t); GT: [512][128] (t,k).
__global__ __launch_bounds__(256) void tables_k(us* __restrict__ FT,
                                                us* __restrict__ GT)
{
    int idx = blockIdx.x * 256 + threadIdx.x;   // 0..65535
    {
        int mm = idx >> 9, t = idx & 511;
        int m = mm & 63;
        float ang = (float)((m * t) & 511) * (6.283185307179586f / 512.f);
        FT[idx] = f2b((mm < 64) ? cosf(ang) : -sinf(ang));
    }
    {
        int t = idx >> 7, k = idx & 127;
        int m = k & 63;
        float ang = (float)((m * t) & 511) * (6.283185307179586f / 512.f);
        float v;
        if (k < 64) v = (m == 0) ? (1.f / 512.f) : (2.f / 512.f) * cosf(ang);
        else        v = (m == 0) ? 0.f : -(2.f / 512.f) * sinf(ang);
        GT[idx] = f2b(v);
    }
}

// peb[t][d] = b_embed[d] + posenc(t,d)
__global__ __launch_bounds__(256) void pe_k(const float* __restrict__ b_embed,
                                            float* __restrict__ peb)
{
    int idx = blockIdx.x * 256 + threadIdx.x;   // 0..262143
    int t = idx >> 9, d = idx & 511;
    float wd = __expf(-(float)(d & ~1) * (9.210340371976184f / 512.f));
    float ang = (float)t * wd;
    peb[idx] = b_embed[d] + ((d & 1) ? cosf(ang) : sinf(ang));
}

// fp32 -> bf16 weights
__global__ __launch_bounds__(256) void f2b_k(const float* __restrict__ in,
                                             us* __restrict__ out, int n4)
{
    int i = blockIdx.x * 256 + threadIdx.x;
    int stride = gridDim.x * 256;
    for (; i < n4; i += stride) {
        float4 v = ((const float4*)in)[i];
        ushort4 o;
        o.x = f2b(v.x); o.y = f2b(v.y); o.z = f2b(v.z); o.w = f2b(v.w);
        ((ushort4*)out)[i] = o;
    }
}

// Pack fw_re/fw_im into uint (lo16 = re bf16, hi16 = im bf16), native layout.
__global__ __launch_bounds__(256) void packw_k(const float* __restrict__ re,
                                               const float* __restrict__ im,
                                               unsigned* __restrict__ wc, int n)
{
    int i = blockIdx.x * 256 + threadIdx.x;
    int stride = gridDim.x * 256;
    for (; i < n; i += stride) {
        unsigned u = (unsigned)f2b(re[i]) | ((unsigned)f2b(im[i]) << 16);
        wc[i] = u;
    }
}

// W_embed [512][200] fp32 -> [512][224] bf16 zero-padded
__global__ __launch_bounds__(256) void we_k(const float* __restrict__ W,
                                            us* __restrict__ Wb)
{
    int idx = blockIdx.x * 256 + threadIdx.x;   // 0..114687
    int d = idx / 224, n = idx - d * 224;
    Wb[idx] = f2b(n < 200 ? W[d * 200 + n] : 0.f);
}

// x [32][200][512] fp32 -> xT [32][512][224] bf16 (zero-padded K)
__global__ __launch_bounds__(256) void xt_k(const float* __restrict__ x,
                                            us* __restrict__ xT)
{
    const int b = blockIdx.x;     // 32
    const int t0 = blockIdx.y * 64;
    const int tid = threadIdx.x;
    __shared__ us ls[64][228];
    const int tt = tid & 63, ng = tid >> 6;
    for (int c = 0; c < 50; ++c) {
        int n = c * 4 + ng;       // 0..199
        ls[tt][n] = f2b(x[((long long)b * 200 + n) * 512 + t0 + tt]);
    }
    for (int c = 0; c < 6; ++c) ls[tt][200 + c * 4 + ng] = 0;
    __syncthreads();
    for (int idx = tid; idx < 64 * 224; idx += 256) {
        int t = idx / 224, n = idx - t * 224;
        xT[((long long)b * 512 + t0 + t) * 224 + n] = ls[t][n];
    }
}

// Mode mix: Y[b,h,o,m] = sum_i XftT[b][m'][h*64+i] * w[h,i,o,m]  (complex).
// XftT layout: [b][mm=128][hi=512]; rows 0..63 = re, 64..127 = im.
// Packed-uint weights: one u32 = (re bf16 | im bf16 << 16); per-h slice 4MB
// = one XCD L2. Grid (256, 2): x -> (h = &7, b = >>3), y -> o-half.
__global__ __launch_bounds__(256) void modemix_k(
    const us* __restrict__ XftT, const unsigned* __restrict__ wc,
    us* __restrict__ Y)
{
    const int h = blockIdx.x & 7, b = blockIdx.x >> 3;
    const int oh = blockIdx.y;       // 0..1
    const int tid = threadIdx.x;
    const int wave = tid >> 6, lane = tid & 63;
    __shared__ float2 xs[64][65];    // [i][m] re,im (padded)

    const us* xp = XftT + (long long)b * 65536 + h * 64;
    for (int c = 0; c < 32; ++c) {
        int row = wave * 32 + c;     // 0..127 (mm)
        float v = b2f(xp[(long long)row * 512 + lane]);
        if (row < 64) xs[lane][row].x = v;
        else          xs[lane][row - 64].y = v;
    }
    __syncthreads();

    const unsigned* wb = wc + (long long)h * 262144 + lane;
    for (int ogl = 0; ogl < 2; ++ogl) {
        const int o = wave * 16 + (oh * 2 + ogl) * 4;
        float ar0 = 0, ai0 = 0, ar1 = 0, ai1 = 0;
        float ar2 = 0, ai2 = 0, ar3 = 0, ai3 = 0;
        const unsigned* wrow = wb + o * 64;
        #pragma unroll 8
        for (int i = 0; i < 64; ++i) {
            float2 xv = xs[i][lane];
            unsigned u0 = wrow[i * 4096];
            unsigned u1 = wrow[i * 4096 + 64];
            unsigned u2 = wrow[i * 4096 + 128];
            unsigned u3 = wrow[i * 4096 + 192];
            float wr, wi;
            wr = __uint_as_float(u0 << 16); wi = __uint_as_float(u0 & 0xFFFF0000u);
            ar0 += xv.x * wr - xv.y * wi;  ai0 += xv.x * wi + xv.y * wr;
            wr = __uint_as_float(u1 << 16); wi = __uint_as_float(u1 & 0xFFFF0000u);
            ar1 += xv.x * wr - xv.y * wi;  ai1 += xv.x * wi + xv.y * wr;
            wr = __uint_as_float(u2 << 16); wi = __uint_as_float(u2 & 0xFFFF0000u);
            ar2 += xv.x * wr - xv.y * wi;  ai2 += xv.x * wi + xv.y * wr;
            wr = __uint_as_float(u3 << 16); wi = __uint_as_float(u3 & 0xFFFF0000u);
            ar3 += xv.x * wr - xv.y * wi;  ai3 += xv.x * wi + xv.y * wr;
        }
        us* yp = Y + (((long long)b * 512 + h * 64 + o) << 7);
        yp[lane]       = f2b(ar0);  yp[64 + lane]       = f2b(ai0);
        yp[128 + lane] = f2b(ar1);  yp[192 + lane]      = f2b(ai1);
        yp[256 + lane] = f2b(ar2);  yp[320 + lane]      = f2b(ai2);
        yp[384 + lane] = f2b(ar3);  yp[448 + lane]      = f2b(ai3);
    }
}

// Pool stage 1: partial[b][g][d] = sum over 64 t-rows
__global__ __launch_bounds__(256) void pool_k(const float* __restrict__ act,
                                              float* __restrict__ partial)
{
    const int b = blockIdx.x, g = blockIdx.y;
    const float* A = act + (long long)b * 262144 + (long long)g * 64 * 512;
    const int d = threadIdx.x;
    float s0 = 0.f, s1 = 0.f;
    for (int t = 0; t < 64; ++t) {
        s0 += A[t * 512 + d];
        s1 += A[t * 512 + 256 + d];
    }
    float* P = partial + ((long long)b * 8 + g) * 512;
    P[d] = s0;
    P[256 + d] = s1;
}

// Pool stage 2 + head
__global__ __launch_bounds__(256) void head2_k(
    const float* __restrict__ partial, const float* __restrict__ Wh,
    const float* __restrict__ bh, float* __restrict__ out)
{
    const int b = blockIdx.x;
    const int tid = threadIdx.x;
    __shared__ float red[256];
    __shared__ float pooled[512];
    for (int d = tid; d < 512; d += 256) {
        float p = 0.f;
        for (int g = 0; g < 8; ++g) p += partial[((long long)b * 8 + g) * 512 + d];
        pooled[d] = p * (1.f / 512.f);
    }
    __syncthreads();
    for (int c = 0; c < 2; ++c) {
        float s = 0.f;
        for (int d = tid; d < 512; d += 256) s += pooled[d] * Wh[c * 512 + d];
        red[tid] = s;
        __syncthreads();
        for (int off = 128; off > 0; off >>= 1) {
            if (tid < off) red[tid] += red[tid + off];
            __syncthreads();
        }
        if (tid == 0) out[b * 2 + c] = red[0] + bh[c];
        __syncthreads();
    }
}

extern "C" void kernel_launch(void* const* d_in, const int* in_sizes, int n_in,
                              void* d_out, int out_size, void* d_ws, size_t ws_size,
                              hipStream_t stream)
{
    const float* x       = (const float*)d_in[0];   // (32,200,512)
    const float* W_embed = (const float*)d_in[1];   // (512,200)
    const float* b_embed = (const float*)d_in[2];   // (512,)
    const float* Wproj   = (const float*)d_in[3];   // (4,512,512)
    const float* bproj   = (const float*)d_in[4];   // (4,512)
    const float* fw_re   = (const float*)d_in[5];   // (4,8,64,64,64)
    const float* fw_im   = (const float*)d_in[6];
    const float* W1      = (const float*)d_in[7];   // (4,2048,512)
    const float* W2      = (const float*)d_in[8];   // (4,512,2048)
    const float* Wh      = (const float*)d_in[9];   // (2,512)
    const float* bh      = (const float*)d_in[10];  // (2,)
    float* out = (float*)d_out;

    float* act = (float*)d_ws;                 // 8388608 f
    us* actb  = (us*)(act + 8388608);          // 8388608 us
    us* actbT = actb + 8388608;                // 8388608
    us* Zb    = actbT + 8388608;               // 2097152
    us* XftT  = Zb + 2097152;                  // 2097152
    us* Yb    = XftT + 2097152;                // 2097152
    us* FT    = Yb + 2097152;                  // 65536
    us* GT    = FT + 65536;                    // 65536
    us* Wpb   = GT + 65536;                    // 1048576
    us* W1b   = Wpb + 1048576;                 // 4194304
    us* W2b   = W1b + 4194304;                 // 4194304
    us* WEb   = W2b + 4194304;                 // 114688
    us* xTb   = WEb + 114688;                  // 3670016
    unsigned* wcp = (unsigned*)(xTb + 3670016);// 8388608 uint
    float* partial = (float*)(wcp + 8388608);  // 131072 f
    float* peb = partial + 131072;             // 262144 f
    us* ffn1 = (us*)(peb + 262144);            // up to 33554432

    long long used_bytes = (char*)ffn1 - (char*)d_ws;
    long long avail_bf16 = ((long long)ws_size - used_bytes) / 2;
    int chunk = 16384;
    if (avail_bf16 < (long long)16384 * 2048) {
        long long c = (avail_bf16 / 2048) & ~511LL;   // keep 512-row align
        chunk = (c < 512) ? 512 : (int)c;
    }

    tables_k<<<256, 256, 0, stream>>>(FT, GT);
    pe_k<<<1024, 256, 0, stream>>>(b_embed, peb);
    f2b_k<<<1024, 256, 0, stream>>>(Wproj, Wpb, 262144);
    f2b_k<<<2048, 256, 0, stream>>>(W1, W1b, 1048576);
    f2b_k<<<2048, 256, 0, stream>>>(W2, W2b, 1048576);
    packw_k<<<4096, 256, 0, stream>>>(fw_re, fw_im, wcp, 8388608);
    we_k<<<448, 256, 0, stream>>>(W_embed, WEb);
    xt_k<<<dim3(32, 8), 256, 0, stream>>>(x, xTb);

    // Embed (MFMA): act = xT @ WEb^T + peb; transposed shadow -> actbT
    mgemm_k<4, 64, 128><<<dim3(4, 8, 32), 256, 0, stream>>>(
        xTb, WEb, act, actbT, 512, 512, 224,
        114688LL, 0LL, 262144LL, peb, 0LL);

    for (int l = 0; l < 4; ++l) {
        const us* Wp = Wpb + (long long)l * 262144;
        const float* bp = bproj + (long long)l * 512;
        const unsigned* wl = wcp + (long long)l * 2097152;
        const us* w1 = W1b + (long long)l * 1048576;
        const us* w2 = W2b + (long long)l * 1048576;

        // truncated DFT: Z[b][mm][d] = sum_t FT[mm][t] * actbT[b][d][t]
        mgemm_k<0, 64, 64, 64><<<dim3(8, 2, 32), 256, 0, stream>>>(
            FT, actbT, Zb, nullptr, 128, 512, 512,
            0LL, 262144LL, 65536LL, nullptr, 0LL);

        // spectral projection: XftT[b][mm][hi] (+512*bp[hi] on DC row)
        mgemm_k<6, 64, 64, 64><<<dim3(8, 2, 32), 256, 0, stream>>>(
            Zb, Wp, XftT, nullptr, 128, 512, 512,
            65536LL, 0LL, 65536LL, bp, 0LL);

        modemix_k<<<dim3(256, 2), 256, 0, stream>>>(XftT, wl, Yb);

        // iDFT + residual: act += GT @ Y^T; plain shadow -> actb (FFN1 input)
        mgemm_k<3, 64, 128><<<dim3(4, 8, 32), 256, 0, stream>>>(
            GT, Yb, act, actb, 512, 512, 128,
            0LL, 65536LL, 262144LL, nullptr, 0LL);

        // FFN
        for (int r0 = 0; r0 < 16384; r0 += chunk) {
            int rows = 16384 - r0 < chunk ? 16384 - r0 : chunk;
            mgemm_k<2, 128, 128><<<dim3(16, rows / 128, 1), 256, 0, stream>>>(
                actb + (long long)r0 * 512, w1, ffn1, nullptr, rows, 2048, 512,
                0LL, 0LL, 0LL, nullptr, 0LL);
            if (l < 3) {
                // act += ffn1 @ W2^T; transposed shadow -> actbT (next layer)
                mgemm_k<7, 128, 128, 64><<<dim3(4, rows / 128, 1), 256, 0, stream>>>(
                    ffn1, w2, act + (long long)r0 * 512,
                    actbT, rows, 512, 2048,
                    0LL, 0LL, 0LL, nullptr, (long long)r0);
            } else {
                mgemm_k<5, 128, 128, 64><<<dim3(4, rows / 128, 1), 256, 0, stream>>>(
                    ffn1, w2, act + (long long)r0 * 512,
                    nullptr, rows, 512, 2048,
                    0LL, 0LL, 0LL, nullptr, 0LL);
            }
        }
    }

    pool_k<<<dim3(32, 8), 256, 0, stream>>>(act, partial);
    head2_k<<<32, 256, 0, stream>>>(partial, Wh, bh, out);
}

// Round 20
// 746.386 us; speedup vs baseline: 1.0111x; 1.0111x over previous
//
#include <hip/hip_runtime.h>
#include <hip/hip_bf16.h>

// ---------------------------------------------------------------------------
// FEDformer forward — FINAL (r18 configuration, best measured: 750 us).
// bf16 MFMA everywhere, fp32 residual stream + bf16 shadow.
// DFT-first spectral path. mgemm: 2-buffer 2-barrier counted-vmcnt pipeline
// + chunk-XOR LDS swizzle + bijective XCD block swizzle. BK=64 where
// grid-limited (FFN2, DFT, spectral); FFN1 BK=32 (LDS-capped occupancy).
// modemix reads PACKED bf16-pair weights (4MB/h = one XCD L2 slice).
// s_setprio reverted (r19 A/B: null/slightly negative).
// B=32, N_NODES=200, T=512, D=512, H=8, HD=64, MODES=64, L=4, D_CONV=2048.
// ---------------------------------------------------------------------------

typedef short s16x8 __attribute__((ext_vector_type(8)));
typedef float f32x4 __attribute__((ext_vector_type(4)));
typedef unsigned short us;

#define GLOAD16(gp, lp)                                                        \
    __builtin_amdgcn_global_load_lds(                                          \
        (const __attribute__((address_space(1))) void*)(gp),                   \
        (__attribute__((address_space(3))) void*)(lp), 16, 0, 0)

__device__ __forceinline__ us f2b(float v) {
    __hip_bfloat16 h = __float2bfloat16(v);
    return *(us*)&h;
}
__device__ __forceinline__ float b2f(us u) {
    __hip_bfloat16_raw r; r.x = u;
    return __bfloat162float(__hip_bfloat16(r));
}

template <int N> __device__ __forceinline__ void vmwait() {
    if constexpr (N == 0)      asm volatile("s_waitcnt vmcnt(0)" ::: "memory");
    else if constexpr (N == 2) asm volatile("s_waitcnt vmcnt(2)" ::: "memory");
    else if constexpr (N == 3) asm volatile("s_waitcnt vmcnt(3)" ::: "memory");
    else if constexpr (N == 4) asm volatile("s_waitcnt vmcnt(4)" ::: "memory");
    else if constexpr (N == 6) asm volatile("s_waitcnt vmcnt(6)" ::: "memory");
    else if constexpr (N == 8) asm volatile("s_waitcnt vmcnt(8)" ::: "memory");
    else                       asm volatile("s_waitcnt vmcnt(0)" ::: "memory");
}

// EPI: 0 = bf16 store, 2 = relu bf16 store,
//      3 = fp32 C += acc + plain bf16 shadow (iDFT),
//      4 = fp32 store (acc + peb) + TRANSPOSED shadow (embed),
//      5 = fp32 C += acc (no shadow, last FFN2),
//      6 = bf16 store + DC-row bias (spectral), 7 = fp32 C += acc +
//      TRANSPOSED shadow (FFN2 l<3).
// Tile: BM x BN x BK, 4 waves 2x2; NT GEMM C[m][n] = sum_k A[m][k]*B[n][k].
// Logical grid: n fastest, then m, then batch — decoded from an XCD-swizzled
// flat id so logically-adjacent (A-sharing) blocks land on the same XCD.
template <int EPI, int BM, int BN, int BK = 32>
__global__ __launch_bounds__(256) void mgemm_k(
    const us* __restrict__ Ap, const us* __restrict__ Bp,
    void* __restrict__ Cp, us* __restrict__ Sp, int M, int N, int K,
    long long a_batch, long long b_batch, long long c_batch,
    const float* __restrict__ bias, long long srow)
{
    constexpr int WM = BM / 2;
    constexpr int WN = BN / 2;
    constexpr int MI = WM / 16;
    constexpr int NJ = WN / 16;
    constexpr int KS = BK / 32;               // k-slices per K-step (1 or 2)
    constexpr int LA = BM * BK / 512;         // A global_load_lds per stage
    constexpr int LB = BN * BK / 512;
    constexpr int LT = LA + LB;               // divisible by 4
    constexpr int LPW = LT / 4;               // loads per wave per stage
    constexpr int HALF = (BM + BN) * BK;      // us per staging buffer
    constexpr int EBS = BN + 2;               // epilogue LDS row stride (f32)
    constexpr int SG = 2 * HALF * 2;
    constexpr int SE = 32 * EBS * 4;
    constexpr int SMEM = SG > SE ? SG : SE;
    __shared__ __align__(16) char smem[SMEM];
    float* eb = (float*)smem;

    // ---- bijective XCD swizzle: physical p -> logical fid ----
    const int gx = gridDim.x, gy = gridDim.y;
    const int tot = gx * gy * gridDim.z;
    int p = (blockIdx.z * gy + blockIdx.y) * gx + blockIdx.x;
    int fid = ((tot & 7) == 0) ? ((p & 7) * (tot >> 3) + (p >> 3)) : p;
    const int bn = fid % gx;
    const int t2 = fid / gx;
    const int bm = t2 % gy;
    const int bz = t2 / gy;

    const us* A = Ap + (long long)bz * a_batch + (long long)bm * BM * K;
    const us* B = Bp + (long long)bz * b_batch + (long long)bn * BN * K;
    const int tid  = threadIdx.x;
    const int wave = tid >> 6, lane = tid & 63;
    const int wr = wave >> 1, wc = wave & 1;

    f32x4 acc[MI][NJ] = {};

    const int frow = lane & 15;

    // staging/read addressing (linear LDS dest, XOR-swizzled global source):
    // BK=32: rows of 64B, 4 chunks of 16B; swizzle s(r) = (r>>1)&3.
    // BK=64: rows of 128B, 8 chunks of 16B; swizzle s(r) = r&7.
    const int r32  = lane >> 2;
    const int kb32 = ((lane & 3) ^ ((lane >> 3) & 3)) * 8;
    const int fko32 = ((lane >> 4) ^ ((frow >> 1) & 3)) * 8;
    const int r64  = lane >> 3;
    const int kb64 = ((lane & 7) ^ (lane >> 3)) * 8;

    auto stage = [&](int k0, int bsel) {
        const us* Ag = A + k0;
        const us* Bg = B + k0;
        us* Ad = (us*)smem + bsel * HALF;
        us* Bd = Ad + BM * BK;
        #pragma unroll
        for (int ii = 0; ii < LPW; ++ii) {
            const int i = ii * 4 + wave;
            if constexpr (BK == 32) {
                if (i < LA)
                    GLOAD16(Ag + (long long)(i * 16 + r32) * K + kb32,
                            Ad + i * 512);
                else
                    GLOAD16(Bg + (long long)((i - LA) * 16 + r32) * K + kb32,
                            Bd + (i - LA) * 512);
            } else {
                if (i < LA)
                    GLOAD16(Ag + (long long)(i * 8 + r64) * K + kb64,
                            Ad + i * 512);
                else
                    GLOAD16(Bg + (long long)((i - LA) * 8 + r64) * K + kb64,
                            Bd + (i - LA) * 512);
            }
        }
    };

    const int NK = K / BK;
    stage(0, 0);
    int cur = 0;
    for (int k = 0; k < NK; ++k) {
        if (k + 1 < NK) {
            stage((k + 1) * BK, cur ^ 1);  // loads span the whole iteration
            vmwait<LPW>();                 // only buf-cur loads (oldest) done
        } else {
            vmwait<0>();
        }
        __builtin_amdgcn_s_barrier();      // buf cur fully staged (all waves)

        const us* Ab = (const us*)smem + cur * HALF;
        const us* Bb = Ab + BM * BK;
        s16x8 af[MI][KS], bfr[NJ][KS];
        if constexpr (BK == 32) {
            #pragma unroll
            for (int i = 0; i < MI; ++i)
                af[i][0] = *(const s16x8*)
                    &Ab[(wr * WM + i * 16 + frow) * 32 + fko32];
            #pragma unroll
            for (int j = 0; j < NJ; ++j)
                bfr[j][0] = *(const s16x8*)
                    &Bb[(wc * WN + j * 16 + frow) * 32 + fko32];
        } else {
            #pragma unroll
            for (int ks = 0; ks < KS; ++ks) {
                const int off = (((ks * 4 + (lane >> 4)) ^ (frow & 7))) * 8;
                #pragma unroll
                for (int i = 0; i < MI; ++i)
                    af[i][ks] = *(const s16x8*)
                        &Ab[(wr * WM + i * 16 + frow) * 64 + off];
                #pragma unroll
                for (int j = 0; j < NJ; ++j)
                    bfr[j][ks] = *(const s16x8*)
                        &Bb[(wc * WN + j * 16 + frow) * 64 + off];
            }
        }
        #pragma unroll
        for (int i = 0; i < MI; ++i)
            #pragma unroll
            for (int j = 0; j < NJ; ++j)
                #pragma unroll
                for (int ks = 0; ks < KS; ++ks)
                    acc[i][j] = __builtin_amdgcn_mfma_f32_16x16x32_bf16(
                        af[i][ks], bfr[j][ks], acc[i][j], 0, 0, 0);

        __builtin_amdgcn_s_barrier();      // all reads of cur done (no drain)
        cur ^= 1;
    }

    // ---- coalesced epilogue: BM/32 passes of 32 rows through LDS ----
    const long long Coff = (long long)bz * c_batch;
    const int row_blk = bm * BM;
    const int col_blk = bn * BN;
    constexpr int RPI = 256 / BN;
    #pragma unroll
    for (int pp = 0; pp < BM / 32; ++pp) {
        __syncthreads();
        #pragma unroll
        for (int rb2 = 0; rb2 < 2; ++rb2) {
            const int rb = pp * 2 + rb2;
            if (wr == rb / MI) {
                const int io = rb % MI;
                #pragma unroll
                for (int j = 0; j < NJ; ++j) {
                    #pragma unroll
                    for (int rr = 0; rr < 4; ++rr) {
                        const int lrow = rb2 * 16 + (lane >> 4) * 4 + rr;
                        const int lcol = wc * WN + j * 16 + (lane & 15);
                        eb[lrow * EBS + lcol] = acc[io][j][rr];
                    }
                }
            }
        }
        __syncthreads();
        #pragma unroll
        for (int it = 0; it < 32 / RPI; ++it) {
            const int lrow = it * RPI + tid / BN;
            const int row  = row_blk + pp * 32 + lrow;
            const int col  = col_blk + (tid % BN);
            float v = eb[lrow * EBS + (tid % BN)];
            const long long cidx = Coff + (long long)row * N + col;
            if (EPI == 0) {
                ((us*)Cp)[cidx] = f2b(v);
            } else if (EPI == 2) {
                ((us*)Cp)[cidx] = f2b(fmaxf(v, 0.f));
            } else if (EPI == 3) {
                float nv = ((float*)Cp)[cidx] + v;
                ((float*)Cp)[cidx] = nv;
                Sp[cidx] = f2b(nv);
            } else if (EPI == 4) {
                float nv = v + bias[(long long)row * 512 + col];
                ((float*)Cp)[cidx] = nv;
                eb[lrow * EBS + (tid % BN)] = nv;    // for transposed pass
            } else if (EPI == 5) {
                ((float*)Cp)[cidx] += v;
            } else if (EPI == 6) {
                if (row == 0) v += 512.f * bias[col];
                ((us*)Cp)[cidx] = f2b(v);
            } else {  // EPI == 7
                float nv = ((float*)Cp)[cidx] + v;
                ((float*)Cp)[cidx] = nv;
                eb[lrow * EBS + (tid % BN)] = nv;    // for transposed pass
            }
        }
        if constexpr (EPI == 4 || EPI == 7) {
            // transposed shadow: Sp[b][d][t], 32 t x BN d tile
            __syncthreads();
            constexpr int TPC = 256 / BN;          // threads per column
            constexpr int RPT = 32 / TPC;          // rows per thread
            const int dl = tid / TPC;              // 0..BN-1
            const int th = (tid % TPC) * RPT;      // starting row
            const long long R = (long long)bz * M + srow
                              + row_blk + pp * 32; // global row (b*512+t)
            const int bb = (int)(R >> 9);
            const int tb = (int)(R & 511);
            us* tp = Sp + (long long)bb * 262144
                        + (long long)(col_blk + dl) * 512 + tb + th;
            #pragma unroll
            for (int v8 = 0; v8 < RPT / 8; ++v8) {
                s16x8 vv;
                #pragma unroll
                for (int i = 0; i < 8; ++i)
                    vv[i] = (short)f2b(eb[(th + v8 * 8 + i) * EBS + dl]);
                *(s16x8*)(tp + v8 * 8) = vv;
            }
        }
    }
}

// Build bf16 DFT tables. FT: [128][512] (mm,t); GT: [512][128] (t,k).
__global__ __launch_bounds__(256) void tables_k(us* __restrict__ FT,
                                                us* __restrict__ GT)
{
    int idx = blockIdx.x * 256 + threadIdx.x;   // 0..65535
    {
        int mm = idx >> 9, t = idx & 511;
        int m = mm & 63;
        float ang = (float)((m * t) & 511) * (6.283185307179586f / 512.f);
        FT[idx] = f2b((mm < 64) ? cosf(ang) : -sinf(ang));
    }
    {
        int t = idx >> 7, k = idx & 127;
        int m = k & 63;
        float ang = (float)((m * t) & 511) * (6.283185307179586f / 512.f);
        float v;
        if (k < 64) v = (m == 0) ? (1.f / 512.f) : (2.f / 512.f) * cosf(ang);
        else        v = (m == 0) ? 0.f : -(2.f / 512.f) * sinf(ang);
        GT[idx] = f2b(v);
    }
}

// peb[t][d] = b_embed[d] + posenc(t,d)
__global__ __launch_bounds__(256) void pe_k(const float* __restrict__ b_embed,
                                            float* __restrict__ peb)
{
    int idx = blockIdx.x * 256 + threadIdx.x;   // 0..262143
    int t = idx >> 9, d = idx & 511;
    float wd = __expf(-(float)(d & ~1) * (9.210340371976184f / 512.f));
    float ang = (float)t * wd;
    peb[idx] = b_embed[d] + ((d & 1) ? cosf(ang) : sinf(ang));
}

// fp32 -> bf16 weights
__global__ __launch_bounds__(256) void f2b_k(const float* __restrict__ in,
                                             us* __restrict__ out, int n4)
{
    int i = blockIdx.x * 256 + threadIdx.x;
    int stride = gridDim.x * 256;
    for (; i < n4; i += stride) {
        float4 v = ((const float4*)in)[i];
        ushort4 o;
        o.x = f2b(v.x); o.y = f2b(v.y); o.z = f2b(v.z); o.w = f2b(v.w);
        ((ushort4*)out)[i] = o;
    }
}

// Pack fw_re/fw_im into uint (lo16 = re bf16, hi16 = im bf16), native layout.
__global__ __launch_bounds__(256) void packw_k(const float* __restrict__ re,
                                               const float* __restrict__ im,
                                               unsigned* __restrict__ wc, int n)
{
    int i = blockIdx.x * 256 + threadIdx.x;
    int stride = gridDim.x * 256;
    for (; i < n; i += stride) {
        unsigned u = (unsigned)f2b(re[i]) | ((unsigned)f2b(im[i]) << 16);
        wc[i] = u;
    }
}

// W_embed [512][200] fp32 -> [512][224] bf16 zero-padded
__global__ __launch_bounds__(256) void we_k(const float* __restrict__ W,
                                            us* __restrict__ Wb)
{
    int idx = blockIdx.x * 256 + threadIdx.x;   // 0..114687
    int d = idx / 224, n = idx - d * 224;
    Wb[idx] = f2b(n < 200 ? W[d * 200 + n] : 0.f);
}

// x [32][200][512] fp32 -> xT [32][512][224] bf16 (zero-padded K)
__global__ __launch_bounds__(256) void xt_k(const float* __restrict__ x,
                                            us* __restrict__ xT)
{
    const int b = blockIdx.x;     // 32
    const int t0 = blockIdx.y * 64;
    const int tid = threadIdx.x;
    __shared__ us ls[64][228];
    const int tt = tid & 63, ng = tid >> 6;
    for (int c = 0; c < 50; ++c) {
        int n = c * 4 + ng;       // 0..199
        ls[tt][n] = f2b(x[((long long)b * 200 + n) * 512 + t0 + tt]);
    }
    for (int c = 0; c < 6; ++c) ls[tt][200 + c * 4 + ng] = 0;
    __syncthreads();
    for (int idx = tid; idx < 64 * 224; idx += 256) {
        int t = idx / 224, n = idx - t * 224;
        xT[((long long)b * 512 + t0 + t) * 224 + n] = ls[t][n];
    }
}

// Mode mix: Y[b,h,o,m] = sum_i XftT[b][m'][h*64+i] * w[h,i,o,m]  (complex).
// XftT layout: [b][mm=128][hi=512]; rows 0..63 = re, 64..127 = im.
// Packed-uint weights: one u32 = (re bf16 | im bf16 << 16); per-h slice 4MB
// = one XCD L2. Grid (256, 2): x -> (h = &7, b = >>3), y -> o-half.
__global__ __launch_bounds__(256) void modemix_k(
    const us* __restrict__ XftT, const unsigned* __restrict__ wc,
    us* __restrict__ Y)
{
    const int h = blockIdx.x & 7, b = blockIdx.x >> 3;
    const int oh = blockIdx.y;       // 0..1
    const int tid = threadIdx.x;
    const int wave = tid >> 6, lane = tid & 63;
    __shared__ float2 xs[64][65];    // [i][m] re,im (padded)

    const us* xp = XftT + (long long)b * 65536 + h * 64;
    for (int c = 0; c < 32; ++c) {
        int row = wave * 32 + c;     // 0..127 (mm)
        float v = b2f(xp[(long long)row * 512 + lane]);
        if (row < 64) xs[lane][row].x = v;
        else          xs[lane][row - 64].y = v;
    }
    __syncthreads();

    const unsigned* wb = wc + (long long)h * 262144 + lane;
    for (int ogl = 0; ogl < 2; ++ogl) {
        const int o = wave * 16 + (oh * 2 + ogl) * 4;
        float ar0 = 0, ai0 = 0, ar1 = 0, ai1 = 0;
        float ar2 = 0, ai2 = 0, ar3 = 0, ai3 = 0;
        const unsigned* wrow = wb + o * 64;
        #pragma unroll 8
        for (int i = 0; i < 64; ++i) {
            float2 xv = xs[i][lane];
            unsigned u0 = wrow[i * 4096];
            unsigned u1 = wrow[i * 4096 + 64];
            unsigned u2 = wrow[i * 4096 + 128];
            unsigned u3 = wrow[i * 4096 + 192];
            float wr, wi;
            wr = __uint_as_float(u0 << 16); wi = __uint_as_float(u0 & 0xFFFF0000u);
            ar0 += xv.x * wr - xv.y * wi;  ai0 += xv.x * wi + xv.y * wr;
            wr = __uint_as_float(u1 << 16); wi = __uint_as_float(u1 & 0xFFFF0000u);
            ar1 += xv.x * wr - xv.y * wi;  ai1 += xv.x * wi + xv.y * wr;
            wr = __uint_as_float(u2 << 16); wi = __uint_as_float(u2 & 0xFFFF0000u);
            ar2 += xv.x * wr - xv.y * wi;  ai2 += xv.x * wi + xv.y * wr;
            wr = __uint_as_float(u3 << 16); wi = __uint_as_float(u3 & 0xFFFF0000u);
            ar3 += xv.x * wr - xv.y * wi;  ai3 += xv.x * wi + xv.y * wr;
        }
        us* yp = Y + (((long long)b * 512 + h * 64 + o) << 7);
        yp[lane]       = f2b(ar0);  yp[64 + lane]       = f2b(ai0);
        yp[128 + lane] = f2b(ar1);  yp[192 + lane]      = f2b(ai1);
        yp[256 + lane] = f2b(ar2);  yp[320 + lane]      = f2b(ai2);
        yp[384 + lane] = f2b(ar3);  yp[448 + lane]      = f2b(ai3);
    }
}

// Pool stage 1: partial[b][g][d] = sum over 64 t-rows
__global__ __launch_bounds__(256) void pool_k(const float* __restrict__ act,
                                              float* __restrict__ partial)
{
    const int b = blockIdx.x, g = blockIdx.y;
    const float* A = act + (long long)b * 262144 + (long long)g * 64 * 512;
    const int d = threadIdx.x;
    float s0 = 0.f, s1 = 0.f;
    for (int t = 0; t < 64; ++t) {
        s0 += A[t * 512 + d];
        s1 += A[t * 512 + 256 + d];
    }
    float* P = partial + ((long long)b * 8 + g) * 512;
    P[d] = s0;
    P[256 + d] = s1;
}

// Pool stage 2 + head
__global__ __launch_bounds__(256) void head2_k(
    const float* __restrict__ partial, const float* __restrict__ Wh,
    const float* __restrict__ bh, float* __restrict__ out)
{
    const int b = blockIdx.x;
    const int tid = threadIdx.x;
    __shared__ float red[256];
    __shared__ float pooled[512];
    for (int d = tid; d < 512; d += 256) {
        float p = 0.f;
        for (int g = 0; g < 8; ++g) p += partial[((long long)b * 8 + g) * 512 + d];
        pooled[d] = p * (1.f / 512.f);
    }
    __syncthreads();
    for (int c = 0; c < 2; ++c) {
        float s = 0.f;
        for (int d = tid; d < 512; d += 256) s += pooled[d] * Wh[c * 512 + d];
        red[tid] = s;
        __syncthreads();
        for (int off = 128; off > 0; off >>= 1) {
            if (tid < off) red[tid] += red[tid + off];
            __syncthreads();
        }
        if (tid == 0) out[b * 2 + c] = red[0] + bh[c];
        __syncthreads();
    }
}

extern "C" void kernel_launch(void* const* d_in, const int* in_sizes, int n_in,
                              void* d_out, int out_size, void* d_ws, size_t ws_size,
                              hipStream_t stream)
{
    const float* x       = (const float*)d_in[0];   // (32,200,512)
    const float* W_embed = (const float*)d_in[1];   // (512,200)
    const float* b_embed = (const float*)d_in[2];   // (512,)
    const float* Wproj   = (const float*)d_in[3];   // (4,512,512)
    const float* bproj   = (const float*)d_in[4];   // (4,512)
    const float* fw_re   = (const float*)d_in[5];   // (4,8,64,64,64)
    const float* fw_im   = (const float*)d_in[6];
    const float* W1      = (const float*)d_in[7];   // (4,2048,512)
    const float* W2      = (const float*)d_in[8];   // (4,512,2048)
    const float* Wh      = (const float*)d_in[9];   // (2,512)
    const float* bh      = (const float*)d_in[10];  // (2,)
    float* out = (float*)d_out;

    float* act = (float*)d_ws;                 // 8388608 f
    us* actb  = (us*)(act + 8388608);          // 8388608 us
    us* actbT = actb + 8388608;                // 8388608
    us* Zb    = actbT + 8388608;               // 2097152
    us* XftT  = Zb + 2097152;                  // 2097152
    us* Yb    = XftT + 2097152;                // 2097152
    us* FT    = Yb + 2097152;                  // 65536
    us* GT    = FT + 65536;                    // 65536
    us* Wpb   = GT + 65536;                    // 1048576
    us* W1b   = Wpb + 1048576;                 // 4194304
    us* W2b   = W1b + 4194304;                 // 4194304
    us* WEb   = W2b + 4194304;                 // 114688
    us* xTb   = WEb + 114688;                  // 3670016
    unsigned* wcp = (unsigned*)(xTb + 3670016);// 8388608 uint
    float* partial = (float*)(wcp + 8388608);  // 131072 f
    float* peb = partial + 131072;             // 262144 f
    us* ffn1 = (us*)(peb + 262144);            // up to 33554432

    long long used_bytes = (char*)ffn1 - (char*)d_ws;
    long long avail_bf16 = ((long long)ws_size - used_bytes) / 2;
    int chunk = 16384;
    if (avail_bf16 < (long long)16384 * 2048) {
        long long c = (avail_bf16 / 2048) & ~511LL;   // keep 512-row align
        chunk = (c < 512) ? 512 : (int)c;
    }

    tables_k<<<256, 256, 0, stream>>>(FT, GT);
    pe_k<<<1024, 256, 0, stream>>>(b_embed, peb);
    f2b_k<<<1024, 256, 0, stream>>>(Wproj, Wpb, 262144);
    f2b_k<<<2048, 256, 0, stream>>>(W1, W1b, 1048576);
    f2b_k<<<2048, 256, 0, stream>>>(W2, W2b, 1048576);
    packw_k<<<4096, 256, 0, stream>>>(fw_re, fw_im, wcp, 8388608);
    we_k<<<448, 256, 0, stream>>>(W_embed, WEb);
    xt_k<<<dim3(32, 8), 256, 0, stream>>>(x, xTb);

    // Embed (MFMA): act = xT @ WEb^T + peb; transposed shadow -> actbT
    mgemm_k<4, 64, 128><<<dim3(4, 8, 32), 256, 0, stream>>>(
        xTb, WEb, act, actbT, 512, 512, 224,
        114688LL, 0LL, 262144LL, peb, 0LL);

    for (int l = 0; l < 4; ++l) {
        const us* Wp = Wpb + (long long)l * 262144;
        const float* bp = bproj + (long long)l * 512;
        const unsigned* wl = wcp + (long long)l * 2097152;
        const us* w1 = W1b + (long long)l * 1048576;
        const us* w2 = W2b + (long long)l * 1048576;

        // truncated DFT: Z[b][mm][d] = sum_t FT[mm][t] * actbT[b][d][t]
        mgemm_k<0, 64, 64, 64><<<dim3(8, 2, 32), 256, 0, stream>>>(
            FT, actbT, Zb, nullptr, 128, 512, 512,
            0LL, 262144LL, 65536LL, nullptr, 0LL);

        // spectral projection: XftT[b][mm][hi] (+512*bp[hi] on DC row)
        mgemm_k<6, 64, 64, 64><<<dim3(8, 2, 32), 256, 0, stream>>>(
            Zb, Wp, XftT, nullptr, 128, 512, 512,
            65536LL, 0LL, 65536LL, bp, 0LL);

        modemix_k<<<dim3(256, 2), 256, 0, stream>>>(XftT, wl, Yb);

        // iDFT + residual: act += GT @ Y^T; plain shadow -> actb (FFN1 input)
        mgemm_k<3, 64, 128><<<dim3(4, 8, 32), 256, 0, stream>>>(
            GT, Yb, act, actb, 512, 512, 128,
            0LL, 65536LL, 262144LL, nullptr, 0LL);

        // FFN
        for (int r0 = 0; r0 < 16384; r0 += chunk) {
            int rows = 16384 - r0 < chunk ? 16384 - r0 : chunk;
            mgemm_k<2, 128, 128><<<dim3(16, rows / 128, 1), 256, 0, stream>>>(
                actb + (long long)r0 * 512, w1, ffn1, nullptr, rows, 2048, 512,
                0LL, 0LL, 0LL, nullptr, 0LL);
            if (l < 3) {
                // act += ffn1 @ W2^T; transposed shadow -> actbT (next layer)
                mgemm_k<7, 128, 128, 64><<<dim3(4, rows / 128, 1), 256, 0, stream>>>(
                    ffn1, w2, act + (long long)r0 * 512,
                    actbT, rows, 512, 2048,
                    0LL, 0LL, 0LL, nullptr, (long long)r0);
            } else {
                mgemm_k<5, 128, 128, 64><<<dim3(4, rows / 128, 1), 256, 0, stream>>>(
                    ffn1, w2, act + (long long)r0 * 512,
                    nullptr, rows, 512, 2048,
                    0LL, 0LL, 0LL, nullptr, 0LL);
            }
        }
    }

    pool_k<<<dim3(32, 8), 256, 0, stream>>>(act, partial);
    head2_k<<<32, 256, 0, stream>>>(partial, Wh, bh, out);
}